// Round 1
// baseline (219.645 us; speedup 1.0000x reference)
//
#include <hip/hip_runtime.h>
#include <math.h>

#define N_    32
#define C_    512
#define P_    1024
#define KG_   10
#define KV_   8
#define PBLK_ 64            // p per block in logits kernel
#define NPB_  (P_ / PBLK_)  // 16
#define PS_   81            // part row stride (conflict-free)

// ---------------------------------------------------------------------------
// Kernel A: logits + softmax. Block = (n, 64-p chunk), 512 threads = 8 waves.
// Wave w reduces c in [w*64, (w+1)*64): w[k][c] indices are wave-uniform ->
// scalar-pipe s_loads. x loads: lane<->p, 256 B contiguous per wave-instr.
// Also zeroes the per-n completion counters used by kernel B's fused finale
// (visibility to B guaranteed by the dispatch boundary).
// ---------------------------------------------------------------------------
__global__ __launch_bounds__(512) void vlad_logits(
    const float* __restrict__ x, const float* __restrict__ w,
    const float* __restrict__ bias, float* __restrict__ a_ws,
    float* __restrict__ asum_blk, int* __restrict__ cnt) {
  __shared__ float part[PBLK_ * PS_];   // 20736 B
  const int t  = threadIdx.x;
  const int pl = t & 63;
  const int cg = __builtin_amdgcn_readfirstlane(threadIdx.x >> 6);  // 0..7
  const int n  = blockIdx.x >> 4;
  const int pb = blockIdx.x & 15;
  const int p0 = pb * PBLK_;

  if (pb == 0 && t == 0) cnt[n] = 0;   // re-zero every iteration

  const float* xp = x + ((size_t)n * C_ + cg * 64) * P_ + p0 + pl;

  float acc[KG_];
#pragma unroll
  for (int k = 0; k < KG_; ++k) acc[k] = 0.f;

#pragma unroll 8
  for (int i = 0; i < 64; ++i) {
    const float xv = xp[(size_t)i * P_];          // coalesced vector load
    const int c = cg * 64 + i;                    // uniform -> s_load for w
#pragma unroll
    for (int k = 0; k < KG_; ++k) acc[k] += xv * w[k * C_ + c];
  }

#pragma unroll
  for (int k = 0; k < KG_; ++k) part[pl * PS_ + cg * KG_ + k] = acc[k];
  __syncthreads();

  if (t < 64) {                                    // wave 0 tail
    float l[KG_];
    float m = -1e30f;
#pragma unroll
    for (int k = 0; k < KG_; ++k) {
      float s = bias[k];
#pragma unroll
      for (int g = 0; g < 8; ++g) s += part[t * PS_ + g * KG_ + k];
      l[k] = s;
      m = fmaxf(m, s);
    }
    float sum = 0.f;
#pragma unroll
    for (int k = 0; k < KG_; ++k) { l[k] = __expf(l[k] - m); sum += l[k]; }
    const float inv = 1.f / sum;
#pragma unroll
    for (int k = 0; k < KV_; ++k) {
      const float a = l[k] * inv;
      a_ws[((size_t)n * KV_ + k) * P_ + p0 + t] = a;   // coalesced
      float s = a;                                     // sum over 64 p (lanes)
      s += __shfl_xor(s, 1, 64);  s += __shfl_xor(s, 2, 64);
      s += __shfl_xor(s, 4, 64);  s += __shfl_xor(s, 8, 64);
      s += __shfl_xor(s, 16, 64); s += __shfl_xor(s, 32, 64);
      if (t == 0) asum_blk[(n * NPB_ + pb) * KV_ + k] = s;
    }
  }
}

// ---------------------------------------------------------------------------
// Kernel B (fused with old kernel C): ax[n][k][c] = sum_p a[n][k][p]*x[n][c][p].
// Block = (n, 16-c slice) over ALL p. x second read is L3-hot; a is L2-hot.
// After writing its ax slice, each block release-fences and bumps cnt[n];
// the 32nd (last) block for that n acquire-fences and runs the finale
// (asum + residual vs centers + L2 normalize + store) with pure wave-level
// reductions: 4 waves x 2 k each, no extra syncthreads. Correct under
// undefined dispatch order; device-scope atomics + fences per G16.
// Grid: N*32 = 1024 blocks of 256 -> 16 waves/CU.
// ---------------------------------------------------------------------------
__global__ __launch_bounds__(256) void vlad_ax_fin(
    const float* __restrict__ x, const float* __restrict__ a_ws,
    const float* __restrict__ asum_blk, const float* __restrict__ centers,
    float* __restrict__ ax_ws, int* __restrict__ cnt,
    float* __restrict__ out) {
  const int n    = blockIdx.x >> 5;
  const int cb   = blockIdx.x & 31;
  const int lane = threadIdx.x & 63;
  const int wv   = threadIdx.x >> 6;
  const int c0   = cb * 16 + wv * 4;

  const float* ap = a_ws + (size_t)n * KV_ * P_;
  const float* xp = x + (size_t)n * C_ * P_;

  float acc[4][8];
#pragma unroll
  for (int cc = 0; cc < 4; ++cc)
#pragma unroll
    for (int k = 0; k < 8; ++k) acc[cc][k] = 0.f;

#pragma unroll
  for (int i = 0; i < 4; ++i) {
    const int pb = i * 256 + lane * 4;
    float4 a4[8];
#pragma unroll
    for (int k = 0; k < 8; ++k)
      a4[k] = *reinterpret_cast<const float4*>(ap + (size_t)k * P_ + pb);
#pragma unroll
    for (int cc = 0; cc < 4; ++cc) {
      float4 x4 = *reinterpret_cast<const float4*>(xp + (size_t)(c0 + cc) * P_ + pb);
#pragma unroll
      for (int k = 0; k < 8; ++k)
        acc[cc][k] += x4.x * a4[k].x + x4.y * a4[k].y
                    + x4.z * a4[k].z + x4.w * a4[k].w;
    }
  }

  // Pack 32 partials, reduce across 64 lanes with value-splitting butterfly.
  float v[32];
#pragma unroll
  for (int cc = 0; cc < 4; ++cc)
#pragma unroll
    for (int k = 0; k < 8; ++k) v[cc * 8 + k] = acc[cc][k];

  {  // step mask=1, keep 16
    const bool hi = lane & 1;
#pragma unroll
    for (int j = 0; j < 16; ++j) {
      float send = hi ? v[j] : v[j + 16];
      float keep = hi ? v[j + 16] : v[j];
      v[j] = keep + __shfl_xor(send, 1, 64);
    }
  }
  {  // mask=2, keep 8
    const bool hi = lane & 2;
#pragma unroll
    for (int j = 0; j < 8; ++j) {
      float send = hi ? v[j] : v[j + 8];
      float keep = hi ? v[j + 8] : v[j];
      v[j] = keep + __shfl_xor(send, 2, 64);
    }
  }
  {  // mask=4, keep 4
    const bool hi = lane & 4;
#pragma unroll
    for (int j = 0; j < 4; ++j) {
      float send = hi ? v[j] : v[j + 4];
      float keep = hi ? v[j + 4] : v[j];
      v[j] = keep + __shfl_xor(send, 4, 64);
    }
  }
  {  // mask=8, keep 2
    const bool hi = lane & 8;
#pragma unroll
    for (int j = 0; j < 2; ++j) {
      float send = hi ? v[j] : v[j + 2];
      float keep = hi ? v[j + 2] : v[j];
      v[j] = keep + __shfl_xor(send, 8, 64);
    }
  }
  {  // mask=16, keep 1
    const bool hi = lane & 16;
    float send = hi ? v[0] : v[1];
    float keep = hi ? v[1] : v[0];
    v[0] = keep + __shfl_xor(send, 16, 64);
  }
  v[0] += __shfl_xor(v[0], 32, 64);

  if (lane < 32) {
    const int o = ((lane & 1) << 4) | ((lane & 2) << 2) | (lane & 4)
                | (((lane >> 3) & 1) << 1) | ((lane >> 4) & 1);
    const int cc = o >> 3;
    const int k  = o & 7;
    ax_ws[((size_t)n * KV_ + k) * C_ + (c0 + cc)] = v[0];
  }

  // ---- completion protocol: last block for this n runs the finale ----
  __threadfence();                       // release: make ax slice visible
  __syncthreads();                       // all threads' stores+fences done
  __shared__ int s_last;
  if (threadIdx.x == 0)
    s_last = (atomicAdd(&cnt[n], 1) == 31) ? 1 : 0;
  __syncthreads();
  if (!s_last) return;
  __threadfence();                       // acquire: see all 32 blocks' ax

  // finale: wave wv handles k = wv and k = wv + 4
#pragma unroll
  for (int kk = 0; kk < 2; ++kk) {
    const int k = wv + kk * 4;

    float asv = 0.f;
#pragma unroll
    for (int pb2 = 0; pb2 < NPB_; ++pb2)          // uniform -> s_loads
      asv += asum_blk[(n * NPB_ + pb2) * KV_ + k];

    float r[8];
    float ss = 0.f;
#pragma unroll
    for (int j = 0; j < 8; ++j) {
      const int c = j * 64 + lane;                // coalesced
      const float av = ax_ws[((size_t)n * KV_ + k) * C_ + c];
      const float ct = centers[k * C_ + c];
      r[j] = av - asv * ct;
      ss += r[j] * r[j];
    }
#pragma unroll
    for (int d = 1; d < 64; d <<= 1) ss += __shfl_xor(ss, d, 64);
    const float inv = 1.f / fmaxf(sqrtf(ss), 1e-12f);
#pragma unroll
    for (int j = 0; j < 8; ++j)
      out[(size_t)n * (KV_ * C_) + k * C_ + j * 64 + lane] = r[j] * inv;
  }
}

extern "C" void kernel_launch(void* const* d_in, const int* in_sizes, int n_in,
                              void* d_out, int out_size, void* d_ws, size_t ws_size,
                              hipStream_t stream) {
  const float* x       = (const float*)d_in[0];
  const float* conv_w  = (const float*)d_in[1];
  const float* conv_b  = (const float*)d_in[2];
  const float* centers = (const float*)d_in[3];
  float* out = (float*)d_out;

  float* a_ws     = (float*)d_ws;                        // 1 MiB
  float* ax_ws    = a_ws + (size_t)N_ * KV_ * P_;        // 512 KiB
  float* asum_blk = ax_ws + (size_t)N_ * KV_ * C_;       // 16 KiB
  int*   cnt      = (int*)(asum_blk + (size_t)N_ * NPB_ * KV_);  // 128 B

  hipLaunchKernelGGL(vlad_logits, dim3(N_ * NPB_), dim3(512), 0, stream,
                     x, conv_w, conv_b, a_ws, asum_blk, cnt);
  hipLaunchKernelGGL(vlad_ax_fin, dim3(N_ * 32),   dim3(256), 0, stream,
                     x, a_ws, asum_blk, centers, ax_ws, cnt, out);
}

// Round 2
// 131.962 us; speedup vs baseline: 1.6645x; 1.6645x over previous
//
#include <hip/hip_runtime.h>
#include <math.h>

#define N_    32
#define C_    512
#define P_    1024
#define KG_   10
#define KV_   8
#define PBLK_ 64            // p per block in fused kernel
#define NPB_  (P_ / PBLK_)  // 16
#define PS_   81            // part row stride (conflict-free)

// ---------------------------------------------------------------------------
// Fused kernel: logits + softmax + partial ax, per (n, 64-p chunk).
// 512 threads = 8 waves. Phase 1 (unchanged from proven A): wave w reduces
// c in [w*64,(w+1)*64); w[k][c] wave-uniform -> s_loads; x loads coalesced
// 256 B/wave-instr. Phase 2: wave-0 softmax tail, a -> LDS (no global a!).
// Phase 3: each wave re-reads ITS OWN 64c x 64p x-tile (L1/L2-hot, same
// addresses as phase 1), forms 32 products/lane (4c x 8k), value-splitting
// butterfly over 64 p-lanes, then plain global atomicAdd of 32 partials
// into ax_ws. NO fences anywhere — round-1 lesson: per-block __threadfence
// serializes the TCC and evicts x; dispatch boundary gives C visibility.
// ax_ws is zeroed by a hipMemsetAsync before this dispatch.
// Grid: N*16 = 512 blocks -> 2 blocks/CU, 16 waves/CU.
// ---------------------------------------------------------------------------
__global__ __launch_bounds__(512) void vlad_fused(
    const float* __restrict__ x, const float* __restrict__ w,
    const float* __restrict__ bias, float* __restrict__ ax_ws,
    float* __restrict__ asum_blk) {
  __shared__ float part[PBLK_ * PS_];   // 20736 B
  __shared__ float a_lds[KV_][64];      // 2 KiB
  const int t  = threadIdx.x;
  const int pl = t & 63;
  const int cg = __builtin_amdgcn_readfirstlane(threadIdx.x >> 6);  // 0..7
  const int n  = blockIdx.x >> 4;
  const int pb = blockIdx.x & 15;
  const int p0 = pb * PBLK_;

  const float* xp = x + ((size_t)n * C_ + cg * 64) * P_ + p0 + pl;

  float acc[KG_];
#pragma unroll
  for (int k = 0; k < KG_; ++k) acc[k] = 0.f;

#pragma unroll 8
  for (int i = 0; i < 64; ++i) {
    const float xv = xp[(size_t)i * P_];          // coalesced vector load
    const int c = cg * 64 + i;                    // uniform -> s_load for w
#pragma unroll
    for (int k = 0; k < KG_; ++k) acc[k] += xv * w[k * C_ + c];
  }

#pragma unroll
  for (int k = 0; k < KG_; ++k) part[pl * PS_ + cg * KG_ + k] = acc[k];
  __syncthreads();

  if (t < 64) {                                    // wave 0 tail
    float l[KG_];
    float m = -1e30f;
#pragma unroll
    for (int k = 0; k < KG_; ++k) {
      float s = bias[k];
#pragma unroll
      for (int g = 0; g < 8; ++g) s += part[t * PS_ + g * KG_ + k];
      l[k] = s;
      m = fmaxf(m, s);
    }
    float sum = 0.f;
#pragma unroll
    for (int k = 0; k < KG_; ++k) { l[k] = __expf(l[k] - m); sum += l[k]; }
    const float inv = 1.f / sum;
#pragma unroll
    for (int k = 0; k < KV_; ++k) {
      const float a = l[k] * inv;
      a_lds[k][t] = a;
      float s = a;                                 // sum over 64 p (lanes)
      s += __shfl_xor(s, 1, 64);  s += __shfl_xor(s, 2, 64);
      s += __shfl_xor(s, 4, 64);  s += __shfl_xor(s, 8, 64);
      s += __shfl_xor(s, 16, 64); s += __shfl_xor(s, 32, 64);
      if (t == 0) asum_blk[(n * NPB_ + pb) * KV_ + k] = s;
    }
  }
  __syncthreads();

  // ---- phase 3: partial ax for this p-chunk, wave w owns c-group w ----
  float ak[KV_];
#pragma unroll
  for (int k = 0; k < KV_; ++k) ak[k] = a_lds[k][pl];  // stride-1, no conflict

  const float* xq = x + (size_t)n * C_ * P_ + p0 + pl; // same lines as phase 1
  float* axn = ax_ws + (size_t)n * KV_ * C_;

  // loop-invariant butterfly predicates and output mapping (hoisted)
  const bool h1 = pl & 1, h2 = pl & 2, h4 = pl & 4, h8 = pl & 8, h16 = pl & 16;
  const int o = ((pl & 1) << 4) | ((pl & 2) << 2) | (pl & 4)
              | (((pl >> 3) & 1) << 1) | ((pl >> 4) & 1);
  const int occ = o >> 3;                // cc this lane writes
  const int ok  = o & 7;                 // k this lane writes

#pragma unroll 2
  for (int q = 0; q < 16; ++q) {
    const int c0 = cg * 64 + q * 4;
    float v[32];
#pragma unroll
    for (int cc = 0; cc < 4; ++cc) {
      const float xv = xq[(size_t)(c0 + cc) * P_];   // L1/L2-hot re-read
#pragma unroll
      for (int k = 0; k < 8; ++k) v[cc * 8 + k] = xv * ak[k];
    }

    // value-splitting butterfly over 64 p-lanes (verified mapping from B)
#pragma unroll
    for (int j = 0; j < 16; ++j) {       // mask=1, keep 16
      float send = h1 ? v[j] : v[j + 16];
      float keep = h1 ? v[j + 16] : v[j];
      v[j] = keep + __shfl_xor(send, 1, 64);
    }
#pragma unroll
    for (int j = 0; j < 8; ++j) {        // mask=2, keep 8
      float send = h2 ? v[j] : v[j + 8];
      float keep = h2 ? v[j + 8] : v[j];
      v[j] = keep + __shfl_xor(send, 2, 64);
    }
#pragma unroll
    for (int j = 0; j < 4; ++j) {        // mask=4, keep 4
      float send = h4 ? v[j] : v[j + 4];
      float keep = h4 ? v[j + 4] : v[j];
      v[j] = keep + __shfl_xor(send, 4, 64);
    }
#pragma unroll
    for (int j = 0; j < 2; ++j) {        // mask=8, keep 2
      float send = h8 ? v[j] : v[j + 2];
      float keep = h8 ? v[j + 2] : v[j];
      v[j] = keep + __shfl_xor(send, 8, 64);
    }
    {                                    // mask=16, keep 1
      float send = h16 ? v[0] : v[1];
      float keep = h16 ? v[1] : v[0];
      v[0] = keep + __shfl_xor(send, 16, 64);
    }
    v[0] += __shfl_xor(v[0], 32, 64);

    if (pl < 32)                         // plain device atomic, no fence
      atomicAdd(&axn[ok * C_ + c0 + occ], v[0]);
  }
}

// ---------------------------------------------------------------------------
// Kernel C (unchanged, proven): asum reduce, residual vs centers, L2
// normalize, write. Grid: N*8 = 256 blocks of 256.
// ---------------------------------------------------------------------------
__global__ __launch_bounds__(256) void vlad_fin(
    const float* __restrict__ ax_ws, const float* __restrict__ asum_blk,
    const float* __restrict__ centers, float* __restrict__ out) {
  __shared__ float sred[4];
  const int n = blockIdx.x >> 3;
  const int k = blockIdx.x & 7;
  const int t = threadIdx.x, lane = t & 63, wv = t >> 6;

  float asv = 0.f;
#pragma unroll
  for (int pb = 0; pb < NPB_; ++pb)                 // uniform -> s_loads
    asv += asum_blk[(n * NPB_ + pb) * KV_ + k];

  const int c = t * 2;
  const float2 av = *reinterpret_cast<const float2*>(&ax_ws[((size_t)n * KV_ + k) * C_ + c]);
  const float2 ct = *reinterpret_cast<const float2*>(&centers[k * C_ + c]);
  const float r0 = av.x - asv * ct.x;
  const float r1 = av.y - asv * ct.y;

  float ss = r0 * r0 + r1 * r1;
#pragma unroll
  for (int d = 1; d < 64; d <<= 1) ss += __shfl_xor(ss, d, 64);
  if (lane == 0) sred[wv] = ss;
  __syncthreads();
  const float tot = (sred[0] + sred[1]) + (sred[2] + sred[3]);
  const float inv = 1.f / fmaxf(sqrtf(tot), 1e-12f);

  out[(size_t)n * (KV_ * C_) + k * C_ + c]     = r0 * inv;
  out[(size_t)n * (KV_ * C_) + k * C_ + c + 1] = r1 * inv;
}

extern "C" void kernel_launch(void* const* d_in, const int* in_sizes, int n_in,
                              void* d_out, int out_size, void* d_ws, size_t ws_size,
                              hipStream_t stream) {
  const float* x       = (const float*)d_in[0];
  const float* conv_w  = (const float*)d_in[1];
  const float* conv_b  = (const float*)d_in[2];
  const float* centers = (const float*)d_in[3];
  float* out = (float*)d_out;

  float* ax_ws    = (float*)d_ws;                        // 512 KiB
  float* asum_blk = ax_ws + (size_t)N_ * KV_ * C_;       // 16 KiB

  hipMemsetAsync(ax_ws, 0, (size_t)N_ * KV_ * C_ * sizeof(float), stream);
  hipLaunchKernelGGL(vlad_fused, dim3(N_ * NPB_), dim3(512), 0, stream,
                     x, conv_w, conv_b, ax_ws, asum_blk);
  hipLaunchKernelGGL(vlad_fin,   dim3(N_ * KV_),  dim3(256), 0, stream,
                     ax_ws, asum_blk, centers, out);
}

// Round 3
// 123.238 us; speedup vs baseline: 1.7823x; 1.0708x over previous
//
#include <hip/hip_runtime.h>
#include <math.h>

#define N_    32
#define C_    512
#define P_    1024
#define KG_   10
#define KV_   8
#define PBLK_ 128           // p per block in fused kernel (2 p per lane)
#define NPB_  (P_ / PBLK_)  // 8 fused blocks per n
#define NSB_  16            // asum slots per n (8 pb x 2 half-waves)
#define PS_   81            // part row stride (odd*? 81 mod 32 = 17 -> conflict-free)

// ---------------------------------------------------------------------------
// Fused kernel: logits + softmax + partial ax, per (n, 128-p chunk).
// 512 threads = 8 waves; wave cg owns c in [cg*64,(cg+1)*64); lane pl owns
// p = p0+2*pl and p0+2*pl+1 (float2 loads, 512 B per wave-instr).
// Row remap for LDS stride-81 conflict-freedom: even-p logits -> row pl,
// odd-p -> row 64+pl (consistent in tail + phase 3; asum order irrelevant).
// Phase 3: butterfly now amortized over 128 p (round-2 lesson: the 6-step
// butterfly per 4c per 64p was 16x kernel-B's shuffle cost -> 56us kernel).
// Partial ax goes to disjoint ax_part[n][pb] slots: deterministic, no
// atomics, no memset. Visibility to kernel C via dispatch boundary (G16).
// Grid: N*8 = 256 blocks -> 1 block/CU, 8 waves/CU.
// ---------------------------------------------------------------------------
__global__ __launch_bounds__(512) void vlad_fused(
    const float* __restrict__ x, const float* __restrict__ w,
    const float* __restrict__ bias, float* __restrict__ ax_part,
    float* __restrict__ asum_blk) {
  __shared__ float part[PBLK_ * PS_];   // 41472 B
  __shared__ float a_lds[KV_][PBLK_];   // 4096 B
  const int t  = threadIdx.x;
  const int pl = t & 63;
  const int cg = __builtin_amdgcn_readfirstlane(threadIdx.x >> 6);  // 0..7
  const int n  = blockIdx.x >> 3;
  const int pb = blockIdx.x & 7;
  const int p0 = pb * PBLK_;

  const float* xp = x + ((size_t)n * C_ + cg * 64) * P_ + p0 + 2 * pl;

  float l0[KG_], l1[KG_];
#pragma unroll
  for (int k = 0; k < KG_; ++k) { l0[k] = 0.f; l1[k] = 0.f; }

#pragma unroll 8
  for (int i = 0; i < 64; ++i) {
    const float2 xv = *reinterpret_cast<const float2*>(&xp[(size_t)i * P_]);
    const int c = cg * 64 + i;                    // uniform -> s_load for w
#pragma unroll
    for (int k = 0; k < KG_; ++k) {
      const float wk = w[k * C_ + c];
      l0[k] += xv.x * wk;
      l1[k] += xv.y * wk;
    }
  }

  // even p -> row pl, odd p -> row 64+pl (both stride-81 conflict-free)
#pragma unroll
  for (int k = 0; k < KG_; ++k) part[pl * PS_ + cg * KG_ + k] = l0[k];
#pragma unroll
  for (int k = 0; k < KG_; ++k) part[(64 + pl) * PS_ + cg * KG_ + k] = l1[k];
  __syncthreads();

  if (t < 128) {                                   // waves 0,1: softmax tail
    const int wv = t >> 6;                         // 0: even-p rows, 1: odd-p
    float l[KG_];
    float m = -1e30f;
#pragma unroll
    for (int k = 0; k < KG_; ++k) {
      float s = bias[k];
#pragma unroll
      for (int g = 0; g < 8; ++g) s += part[t * PS_ + g * KG_ + k];
      l[k] = s;
      m = fmaxf(m, s);
    }
    float sum = 0.f;
#pragma unroll
    for (int k = 0; k < KG_; ++k) { l[k] = __expf(l[k] - m); sum += l[k]; }
    const float inv = 1.f / sum;
#pragma unroll
    for (int k = 0; k < KV_; ++k) {
      const float a = l[k] * inv;
      a_lds[k][t] = a;
      float s = a;                                 // sum over this wave's 64 rows
      s += __shfl_xor(s, 1, 64);  s += __shfl_xor(s, 2, 64);
      s += __shfl_xor(s, 4, 64);  s += __shfl_xor(s, 8, 64);
      s += __shfl_xor(s, 16, 64); s += __shfl_xor(s, 32, 64);
      if ((t & 63) == 0)
        asum_blk[((size_t)n * NSB_ + pb * 2 + wv) * KV_ + k] = s;
    }
  }
  __syncthreads();

  // ---- phase 3: partial ax for this p-chunk, wave cg re-reads its own
  // 64c x 128p tile (L2/L3-hot, same lines as phase 1) ----
  float ak0[KV_], ak1[KV_];
#pragma unroll
  for (int k = 0; k < KV_; ++k) {
    ak0[k] = a_lds[k][pl];        // a at p = p0+2*pl   (row pl)
    ak1[k] = a_lds[k][64 + pl];   // a at p = p0+2*pl+1 (row 64+pl)
  }

  const float* xq = x + (size_t)n * C_ * P_ + p0 + 2 * pl;
  float* axp = ax_part + ((size_t)n * NPB_ + pb) * KV_ * C_;

  // loop-invariant butterfly predicates and output mapping (verified in B)
  const bool h1 = pl & 1, h2 = pl & 2, h4 = pl & 4, h8 = pl & 8, h16 = pl & 16;
  const int o = ((pl & 1) << 4) | ((pl & 2) << 2) | (pl & 4)
              | (((pl >> 3) & 1) << 1) | ((pl >> 4) & 1);
  const int occ = o >> 3;                // cc this lane writes
  const int ok  = o & 7;                 // k this lane writes

#pragma unroll 2
  for (int q = 0; q < 16; ++q) {
    const int c0 = cg * 64 + q * 4;
    float v[32];
#pragma unroll
    for (int cc = 0; cc < 4; ++cc) {
      const float2 xv = *reinterpret_cast<const float2*>(&xq[(size_t)(c0 + cc) * P_]);
#pragma unroll
      for (int k = 0; k < 8; ++k)
        v[cc * 8 + k] = xv.x * ak0[k] + xv.y * ak1[k];
    }

    // value-splitting butterfly over 64 lanes (= 128 p)
#pragma unroll
    for (int j = 0; j < 16; ++j) {       // mask=1, keep 16
      float send = h1 ? v[j] : v[j + 16];
      float keep = h1 ? v[j + 16] : v[j];
      v[j] = keep + __shfl_xor(send, 1, 64);
    }
#pragma unroll
    for (int j = 0; j < 8; ++j) {        // mask=2, keep 8
      float send = h2 ? v[j] : v[j + 8];
      float keep = h2 ? v[j + 8] : v[j];
      v[j] = keep + __shfl_xor(send, 2, 64);
    }
#pragma unroll
    for (int j = 0; j < 4; ++j) {        // mask=4, keep 4
      float send = h4 ? v[j] : v[j + 4];
      float keep = h4 ? v[j + 4] : v[j];
      v[j] = keep + __shfl_xor(send, 4, 64);
    }
#pragma unroll
    for (int j = 0; j < 2; ++j) {        // mask=8, keep 2
      float send = h8 ? v[j] : v[j + 2];
      float keep = h8 ? v[j + 2] : v[j];
      v[j] = keep + __shfl_xor(send, 8, 64);
    }
    {                                    // mask=16, keep 1
      float send = h16 ? v[0] : v[1];
      float keep = h16 ? v[1] : v[0];
      v[0] = keep + __shfl_xor(send, 16, 64);
    }
    v[0] += __shfl_xor(v[0], 32, 64);

    if (pl < 32)                         // disjoint slot: plain store
      axp[ok * C_ + c0 + occ] = v[0];
  }
}

// ---------------------------------------------------------------------------
// Kernel C: sum 8 ax_part slots + 16 asum slots, residual vs centers, L2
// normalize, write. Grid: N*8 = 256 blocks of 256.
// ---------------------------------------------------------------------------
__global__ __launch_bounds__(256) void vlad_fin(
    const float* __restrict__ ax_part, const float* __restrict__ asum_blk,
    const float* __restrict__ centers, float* __restrict__ out) {
  __shared__ float sred[4];
  const int n = blockIdx.x >> 3;
  const int k = blockIdx.x & 7;
  const int t = threadIdx.x, lane = t & 63, wv = t >> 6;

  float asv = 0.f;
#pragma unroll
  for (int s = 0; s < NSB_; ++s)                    // uniform -> s_loads
    asv += asum_blk[((size_t)n * NSB_ + s) * KV_ + k];

  const int c = t * 2;
  float ax0 = 0.f, ax1 = 0.f;
#pragma unroll
  for (int pb = 0; pb < NPB_; ++pb) {               // coalesced float2 loads
    const float2 av = *reinterpret_cast<const float2*>(
        &ax_part[(((size_t)n * NPB_ + pb) * KV_ + k) * C_ + c]);
    ax0 += av.x;
    ax1 += av.y;
  }

  const float2 ct = *reinterpret_cast<const float2*>(&centers[k * C_ + c]);
  const float r0 = ax0 - asv * ct.x;
  const float r1 = ax1 - asv * ct.y;

  float ss = r0 * r0 + r1 * r1;
#pragma unroll
  for (int d = 1; d < 64; d <<= 1) ss += __shfl_xor(ss, d, 64);
  if (lane == 0) sred[wv] = ss;
  __syncthreads();
  const float tot = (sred[0] + sred[1]) + (sred[2] + sred[3]);
  const float inv = 1.f / fmaxf(sqrtf(tot), 1e-12f);

  out[(size_t)n * (KV_ * C_) + k * C_ + c]     = r0 * inv;
  out[(size_t)n * (KV_ * C_) + k * C_ + c + 1] = r1 * inv;
}

extern "C" void kernel_launch(void* const* d_in, const int* in_sizes, int n_in,
                              void* d_out, int out_size, void* d_ws, size_t ws_size,
                              hipStream_t stream) {
  const float* x       = (const float*)d_in[0];
  const float* conv_w  = (const float*)d_in[1];
  const float* conv_b  = (const float*)d_in[2];
  const float* centers = (const float*)d_in[3];
  float* out = (float*)d_out;

  float* ax_part  = (float*)d_ws;                              // 4 MiB
  float* asum_blk = ax_part + (size_t)N_ * NPB_ * KV_ * C_;    // 16 KiB

  hipLaunchKernelGGL(vlad_fused, dim3(N_ * NPB_), dim3(512), 0, stream,
                     x, conv_w, conv_b, ax_part, asum_blk);
  hipLaunchKernelGGL(vlad_fin,   dim3(N_ * KV_),  dim3(256), 0, stream,
                     ax_part, asum_blk, centers, out);
}

// Round 4
// 119.728 us; speedup vs baseline: 1.8345x; 1.0293x over previous
//
#include <hip/hip_runtime.h>
#include <math.h>

#define N_    32
#define C_    512
#define P_    1024
#define KG_   10
#define KV_   8
#define PBLK_ 128           // p per block (2 p per lane)
#define NPB_  (P_ / PBLK_)  // 8 fused blocks per n
#define NSB_  16            // asum slots per n (8 pb x 2 half-p-sets)
#define WVS_  16            // waves per block
#define CW_   32            // c per wave
#define PS_   161           // part row stride (161 mod 32 = 1 -> conflict-free)

// ---------------------------------------------------------------------------
// Fused kernel: logits + softmax + partial ax, per (n, 128-p chunk).
// 1024 threads = 16 waves (round-3 post-mortem: 512-thr/256-blk grid gave
// 2 waves/SIMD -> latency-bound at 1.4 TB/s, Occ 19%). Wave cg owns 32 c's;
// lane pl owns p = p0+2*pl (even, LDS row pl) and p0+2*pl+1 (odd, row 64+pl).
// Phase 1: explicit 8-deep float2 load batches (static-indexed regs) keep
// 8 loads/wave in flight -> 64 KB/CU in-flight, covers HBM latency.
// w[k][c] is wave-uniform -> scalar-pipe s_loads.
// Phase 3: butterfly amortized over 128 p, 8 quads/wave (round-2 lesson).
// Partial ax -> disjoint ax_part[n][pb] slots: no atomics, no fences
// (round-1 lesson: per-block __threadfence serializes TCC), no memset.
// Grid: N*8 = 256 blocks -> 1 block/CU, 16 waves/CU, LDS 86.5 KB.
// ---------------------------------------------------------------------------
__global__ __launch_bounds__(1024) void vlad_fused(
    const float* __restrict__ x, const float* __restrict__ w,
    const float* __restrict__ bias, float* __restrict__ ax_part,
    float* __restrict__ asum_blk) {
  __shared__ float part[PBLK_ * PS_];   // 82432 B
  __shared__ float a_lds[KV_][PBLK_];   // 4096 B
  const int t  = threadIdx.x;
  const int pl = t & 63;
  const int cg = __builtin_amdgcn_readfirstlane(threadIdx.x >> 6);  // 0..15
  const int n  = blockIdx.x >> 3;
  const int pb = blockIdx.x & 7;
  const int p0 = pb * PBLK_;

  const float* xp = x + ((size_t)n * C_ + cg * CW_) * P_ + p0 + 2 * pl;

  float l0[KG_], l1[KG_];
#pragma unroll
  for (int k = 0; k < KG_; ++k) { l0[k] = 0.f; l1[k] = 0.f; }

#pragma unroll
  for (int ch = 0; ch < CW_ / 8; ++ch) {           // 4 chunks of 8 c
    float2 xv[8];                                   // static-indexed -> VGPRs
#pragma unroll
    for (int u = 0; u < 8; ++u)
      xv[u] = *reinterpret_cast<const float2*>(&xp[(size_t)(ch * 8 + u) * P_]);
#pragma unroll
    for (int u = 0; u < 8; ++u) {
      const int c = cg * CW_ + ch * 8 + u;          // uniform -> s_load for w
#pragma unroll
      for (int k = 0; k < KG_; ++k) {
        const float wk = w[k * C_ + c];
        l0[k] += xv[u].x * wk;
        l1[k] += xv[u].y * wk;
      }
    }
  }

  // even p -> row pl, odd p -> row 64+pl (stride 161: conflict-free)
#pragma unroll
  for (int k = 0; k < KG_; ++k) part[pl * PS_ + cg * KG_ + k] = l0[k];
#pragma unroll
  for (int k = 0; k < KG_; ++k) part[(64 + pl) * PS_ + cg * KG_ + k] = l1[k];
  __syncthreads();

  if (t < 128) {                                   // waves 0,1: softmax tail
    const int wv = t >> 6;                         // 0: even-p rows, 1: odd-p
    float l[KG_];
    float m = -1e30f;
#pragma unroll
    for (int k = 0; k < KG_; ++k) {
      float s = bias[k];
#pragma unroll
      for (int g = 0; g < WVS_; ++g) s += part[t * PS_ + g * KG_ + k];
      l[k] = s;
      m = fmaxf(m, s);
    }
    float sum = 0.f;
#pragma unroll
    for (int k = 0; k < KG_; ++k) { l[k] = __expf(l[k] - m); sum += l[k]; }
    const float inv = 1.f / sum;
#pragma unroll
    for (int k = 0; k < KV_; ++k) {
      const float a = l[k] * inv;
      a_lds[k][t] = a;
      float s = a;                                 // sum over this wave's rows
      s += __shfl_xor(s, 1, 64);  s += __shfl_xor(s, 2, 64);
      s += __shfl_xor(s, 4, 64);  s += __shfl_xor(s, 8, 64);
      s += __shfl_xor(s, 16, 64); s += __shfl_xor(s, 32, 64);
      if ((t & 63) == 0)
        asum_blk[((size_t)n * NSB_ + pb * 2 + wv) * KV_ + k] = s;
    }
  }
  __syncthreads();

  // ---- phase 3: partial ax; wave cg re-reads its own 32c x 128p tile
  // (L2/L3-hot, same lines as phase 1) ----
  float ak0[KV_], ak1[KV_];
#pragma unroll
  for (int k = 0; k < KV_; ++k) {
    ak0[k] = a_lds[k][pl];        // a at p = p0+2*pl   (row pl)
    ak1[k] = a_lds[k][64 + pl];   // a at p = p0+2*pl+1 (row 64+pl)
  }

  const float* xq = x + (size_t)n * C_ * P_ + p0 + 2 * pl;
  float* axp = ax_part + ((size_t)n * NPB_ + pb) * KV_ * C_;

  // loop-invariant butterfly predicates and output mapping (verified)
  const bool h1 = pl & 1, h2 = pl & 2, h4 = pl & 4, h8 = pl & 8, h16 = pl & 16;
  const int o = ((pl & 1) << 4) | ((pl & 2) << 2) | (pl & 4)
              | (((pl >> 3) & 1) << 1) | ((pl >> 4) & 1);
  const int occ = o >> 3;                // cc this lane writes
  const int ok  = o & 7;                 // k this lane writes

#pragma unroll 2
  for (int q = 0; q < CW_ / 4; ++q) {    // 8 quads
    const int c0 = cg * CW_ + q * 4;
    float v[32];
#pragma unroll
    for (int cc = 0; cc < 4; ++cc) {
      const float2 xv = *reinterpret_cast<const float2*>(&xq[(size_t)(c0 + cc) * P_]);
#pragma unroll
      for (int k = 0; k < 8; ++k)
        v[cc * 8 + k] = xv.x * ak0[k] + xv.y * ak1[k];
    }

    // value-splitting butterfly over 64 lanes (= 128 p)
#pragma unroll
    for (int j = 0; j < 16; ++j) {       // mask=1, keep 16
      float send = h1 ? v[j] : v[j + 16];
      float keep = h1 ? v[j + 16] : v[j];
      v[j] = keep + __shfl_xor(send, 1, 64);
    }
#pragma unroll
    for (int j = 0; j < 8; ++j) {        // mask=2, keep 8
      float send = h2 ? v[j] : v[j + 8];
      float keep = h2 ? v[j + 8] : v[j];
      v[j] = keep + __shfl_xor(send, 2, 64);
    }
#pragma unroll
    for (int j = 0; j < 4; ++j) {        // mask=4, keep 4
      float send = h4 ? v[j] : v[j + 4];
      float keep = h4 ? v[j + 4] : v[j];
      v[j] = keep + __shfl_xor(send, 4, 64);
    }
#pragma unroll
    for (int j = 0; j < 2; ++j) {        // mask=8, keep 2
      float send = h8 ? v[j] : v[j + 2];
      float keep = h8 ? v[j + 2] : v[j];
      v[j] = keep + __shfl_xor(send, 8, 64);
    }
    {                                    // mask=16, keep 1
      float send = h16 ? v[0] : v[1];
      float keep = h16 ? v[1] : v[0];
      v[0] = keep + __shfl_xor(send, 16, 64);
    }
    v[0] += __shfl_xor(v[0], 32, 64);

    if (pl < 32)                         // disjoint slot: plain store
      axp[ok * C_ + c0 + occ] = v[0];
  }
}

// ---------------------------------------------------------------------------
// Kernel C: sum 8 ax_part slots + 16 asum slots, residual vs centers, L2
// normalize, write. Grid: N*8 = 256 blocks of 256.
// ---------------------------------------------------------------------------
__global__ __launch_bounds__(256) void vlad_fin(
    const float* __restrict__ ax_part, const float* __restrict__ asum_blk,
    const float* __restrict__ centers, float* __restrict__ out) {
  __shared__ float sred[4];
  const int n = blockIdx.x >> 3;
  const int k = blockIdx.x & 7;
  const int t = threadIdx.x, lane = t & 63, wv = t >> 6;

  float asv = 0.f;
#pragma unroll
  for (int s = 0; s < NSB_; ++s)                    // uniform -> s_loads
    asv += asum_blk[((size_t)n * NSB_ + s) * KV_ + k];

  const int c = t * 2;
  float ax0 = 0.f, ax1 = 0.f;
#pragma unroll
  for (int pb = 0; pb < NPB_; ++pb) {               // coalesced float2 loads
    const float2 av = *reinterpret_cast<const float2*>(
        &ax_part[(((size_t)n * NPB_ + pb) * KV_ + k) * C_ + c]);
    ax0 += av.x;
    ax1 += av.y;
  }

  const float2 ct = *reinterpret_cast<const float2*>(&centers[k * C_ + c]);
  const float r0 = ax0 - asv * ct.x;
  const float r1 = ax1 - asv * ct.y;

  float ss = r0 * r0 + r1 * r1;
#pragma unroll
  for (int d = 1; d < 64; d <<= 1) ss += __shfl_xor(ss, d, 64);
  if (lane == 0) sred[wv] = ss;
  __syncthreads();
  const float tot = (sred[0] + sred[1]) + (sred[2] + sred[3]);
  const float inv = 1.f / fmaxf(sqrtf(tot), 1e-12f);

  out[(size_t)n * (KV_ * C_) + k * C_ + c]     = r0 * inv;
  out[(size_t)n * (KV_ * C_) + k * C_ + c + 1] = r1 * inv;
}

extern "C" void kernel_launch(void* const* d_in, const int* in_sizes, int n_in,
                              void* d_out, int out_size, void* d_ws, size_t ws_size,
                              hipStream_t stream) {
  const float* x       = (const float*)d_in[0];
  const float* conv_w  = (const float*)d_in[1];
  const float* conv_b  = (const float*)d_in[2];
  const float* centers = (const float*)d_in[3];
  float* out = (float*)d_out;

  float* ax_part  = (float*)d_ws;                              // 4 MiB
  float* asum_blk = ax_part + (size_t)N_ * NPB_ * KV_ * C_;    // 16 KiB

  hipLaunchKernelGGL(vlad_fused, dim3(N_ * NPB_), dim3(1024), 0, stream,
                     x, conv_w, conv_b, ax_part, asum_blk);
  hipLaunchKernelGGL(vlad_fin,   dim3(N_ * KV_),  dim3(256), 0, stream,
                     ax_part, asum_blk, centers, out);
}

// Round 5
// 117.639 us; speedup vs baseline: 1.8671x; 1.0178x over previous
//
#include <hip/hip_runtime.h>
#include <math.h>

#define N_    32
#define C_    512
#define P_    1024
#define KG_   10
#define KV_   8
#define PBLK_ 128           // p per block (2 p per lane)
#define NPB_  (P_ / PBLK_)  // 8 fused blocks per n
#define NSB_  16            // asum slots per n (8 pb x 2 half-p-sets)
#define WVS_  16            // waves per block
#define CW_   32            // c per wave
#define PS_   161           // part row stride (161 mod 32 = 1 -> conflict-free)

// ---------------------------------------------------------------------------
// Fused kernel: logits + softmax + partial ax, per (n, 128-p chunk).
// 1024 threads = 16 waves. Wave cg owns 32 c's; lane pl owns p = p0+2*pl
// (even, LDS row pl) and p0+2*pl+1 (odd, row 64+pl).
// ROUND-4 LESSON: phase-3's x re-read was served by L3 (32 blocks x 256KB
// = 8MB/XCD footprint evicts L2) at ~2-3 TB/s -> ~25us stall. Fix: keep the
// wave's 32c x 128p x-tile IN REGISTERS (xr[32] float2 = 64 VGPR/lane)
// across the softmax barrier -> x is touched exactly once, phase 3 has
// zero memory traffic. VGPR ~125 <= 128 cap of launch_bounds(1024).
// Phase 3 butterfly amortized over 128 p (round-2 lesson). Partial ax ->
// disjoint ax_part[n][pb] slots: no atomics, no fences (round-1 lesson),
// no memset. Grid: N*8 = 256 blocks -> 1 block/CU, 16 waves/CU.
// ---------------------------------------------------------------------------
__global__ __launch_bounds__(1024) void vlad_fused(
    const float* __restrict__ x, const float* __restrict__ w,
    const float* __restrict__ bias, float* __restrict__ ax_part,
    float* __restrict__ asum_blk) {
  __shared__ float part[PBLK_ * PS_];   // 82432 B
  __shared__ float a_lds[KV_][PBLK_];   // 4096 B
  const int t  = threadIdx.x;
  const int pl = t & 63;
  const int cg = __builtin_amdgcn_readfirstlane(threadIdx.x >> 6);  // 0..15
  const int n  = blockIdx.x >> 3;
  const int pb = blockIdx.x & 7;
  const int p0 = pb * PBLK_;

  const float* xp = x + ((size_t)n * C_ + cg * CW_) * P_ + p0 + 2 * pl;

  float2 xr[CW_];                        // persistent x tile: 64 VGPRs
  float l0[KG_], l1[KG_];
#pragma unroll
  for (int k = 0; k < KG_; ++k) { l0[k] = 0.f; l1[k] = 0.f; }

#pragma unroll
  for (int ch = 0; ch < CW_ / 8; ++ch) {           // 4 batches of 8 loads
#pragma unroll
    for (int u = 0; u < 8; ++u)
      xr[ch * 8 + u] =
          *reinterpret_cast<const float2*>(&xp[(size_t)(ch * 8 + u) * P_]);
#pragma unroll
    for (int u = 0; u < 8; ++u) {
      const int c = cg * CW_ + ch * 8 + u;          // uniform -> s_load for w
      const float2 xv = xr[ch * 8 + u];
#pragma unroll
      for (int k = 0; k < KG_; ++k) {
        const float wk = w[k * C_ + c];
        l0[k] += xv.x * wk;
        l1[k] += xv.y * wk;
      }
    }
  }

  // even p -> row pl, odd p -> row 64+pl (stride 161: conflict-free)
#pragma unroll
  for (int k = 0; k < KG_; ++k) part[pl * PS_ + cg * KG_ + k] = l0[k];
#pragma unroll
  for (int k = 0; k < KG_; ++k) part[(64 + pl) * PS_ + cg * KG_ + k] = l1[k];
  __syncthreads();

  if (t < 128) {                                   // waves 0,1: softmax tail
    const int wv = t >> 6;                         // 0: even-p rows, 1: odd-p
    float l[KG_];
    float m = -1e30f;
#pragma unroll
    for (int k = 0; k < KG_; ++k) {
      float s = bias[k];
#pragma unroll
      for (int g = 0; g < WVS_; ++g) s += part[t * PS_ + g * KG_ + k];
      l[k] = s;
      m = fmaxf(m, s);
    }
    float sum = 0.f;
#pragma unroll
    for (int k = 0; k < KG_; ++k) { l[k] = __expf(l[k] - m); sum += l[k]; }
    const float inv = 1.f / sum;
#pragma unroll
    for (int k = 0; k < KV_; ++k) {
      const float a = l[k] * inv;
      a_lds[k][t] = a;
      float s = a;                                 // sum over this wave's rows
      s += __shfl_xor(s, 1, 64);  s += __shfl_xor(s, 2, 64);
      s += __shfl_xor(s, 4, 64);  s += __shfl_xor(s, 8, 64);
      s += __shfl_xor(s, 16, 64); s += __shfl_xor(s, 32, 64);
      if ((t & 63) == 0)
        asum_blk[((size_t)n * NSB_ + pb * 2 + wv) * KV_ + k] = s;
    }
  }
  __syncthreads();

  // ---- phase 3: partial ax straight from registers (no memory reads) ----
  float ak0[KV_], ak1[KV_];
#pragma unroll
  for (int k = 0; k < KV_; ++k) {
    ak0[k] = a_lds[k][pl];        // a at p = p0+2*pl   (row pl)
    ak1[k] = a_lds[k][64 + pl];   // a at p = p0+2*pl+1 (row 64+pl)
  }

  float* axp = ax_part + ((size_t)n * NPB_ + pb) * KV_ * C_;

  // loop-invariant butterfly predicates and output mapping (verified)
  const bool h1 = pl & 1, h2 = pl & 2, h4 = pl & 4, h8 = pl & 8, h16 = pl & 16;
  const int o = ((pl & 1) << 4) | ((pl & 2) << 2) | (pl & 4)
              | (((pl >> 3) & 1) << 1) | ((pl >> 4) & 1);
  const int occ = o >> 3;                // cc this lane writes
  const int ok  = o & 7;                 // k this lane writes

#pragma unroll
  for (int q = 0; q < CW_ / 4; ++q) {    // 8 quads
    const int c0 = cg * CW_ + q * 4;
    float v[32];
#pragma unroll
    for (int cc = 0; cc < 4; ++cc) {
      const float2 xv = xr[q * 4 + cc];  // registers, not memory
#pragma unroll
      for (int k = 0; k < 8; ++k)
        v[cc * 8 + k] = xv.x * ak0[k] + xv.y * ak1[k];
    }

    // value-splitting butterfly over 64 lanes (= 128 p)
#pragma unroll
    for (int j = 0; j < 16; ++j) {       // mask=1, keep 16
      float send = h1 ? v[j] : v[j + 16];
      float keep = h1 ? v[j + 16] : v[j];
      v[j] = keep + __shfl_xor(send, 1, 64);
    }
#pragma unroll
    for (int j = 0; j < 8; ++j) {        // mask=2, keep 8
      float send = h2 ? v[j] : v[j + 8];
      float keep = h2 ? v[j + 8] : v[j];
      v[j] = keep + __shfl_xor(send, 2, 64);
    }
#pragma unroll
    for (int j = 0; j < 4; ++j) {        // mask=4, keep 4
      float send = h4 ? v[j] : v[j + 4];
      float keep = h4 ? v[j + 4] : v[j];
      v[j] = keep + __shfl_xor(send, 4, 64);
    }
#pragma unroll
    for (int j = 0; j < 2; ++j) {        // mask=8, keep 2
      float send = h8 ? v[j] : v[j + 2];
      float keep = h8 ? v[j + 2] : v[j];
      v[j] = keep + __shfl_xor(send, 8, 64);
    }
    {                                    // mask=16, keep 1
      float send = h16 ? v[0] : v[1];
      float keep = h16 ? v[1] : v[0];
      v[0] = keep + __shfl_xor(send, 16, 64);
    }
    v[0] += __shfl_xor(v[0], 32, 64);

    if (pl < 32)                         // disjoint slot: plain store
      axp[ok * C_ + c0 + occ] = v[0];
  }
}

// ---------------------------------------------------------------------------
// Kernel C: sum 8 ax_part slots + 16 asum slots, residual vs centers, L2
// normalize, write. Grid: N*8 = 256 blocks of 256.
// ---------------------------------------------------------------------------
__global__ __launch_bounds__(256) void vlad_fin(
    const float* __restrict__ ax_part, const float* __restrict__ asum_blk,
    const float* __restrict__ centers, float* __restrict__ out) {
  __shared__ float sred[4];
  const int n = blockIdx.x >> 3;
  const int k = blockIdx.x & 7;
  const int t = threadIdx.x, lane = t & 63, wv = t >> 6;

  float asv = 0.f;
#pragma unroll
  for (int s = 0; s < NSB_; ++s)                    // uniform -> s_loads
    asv += asum_blk[((size_t)n * NSB_ + s) * KV_ + k];

  const int c = t * 2;
  float ax0 = 0.f, ax1 = 0.f;
#pragma unroll
  for (int pb = 0; pb < NPB_; ++pb) {               // coalesced float2 loads
    const float2 av = *reinterpret_cast<const float2*>(
        &ax_part[(((size_t)n * NPB_ + pb) * KV_ + k) * C_ + c]);
    ax0 += av.x;
    ax1 += av.y;
  }

  const float2 ct = *reinterpret_cast<const float2*>(&centers[k * C_ + c]);
  const float r0 = ax0 - asv * ct.x;
  const float r1 = ax1 - asv * ct.y;

  float ss = r0 * r0 + r1 * r1;
#pragma unroll
  for (int d = 1; d < 64; d <<= 1) ss += __shfl_xor(ss, d, 64);
  if (lane == 0) sred[wv] = ss;
  __syncthreads();
  const float tot = (sred[0] + sred[1]) + (sred[2] + sred[3]);
  const float inv = 1.f / fmaxf(sqrtf(tot), 1e-12f);

  out[(size_t)n * (KV_ * C_) + k * C_ + c]     = r0 * inv;
  out[(size_t)n * (KV_ * C_) + k * C_ + c + 1] = r1 * inv;
}

extern "C" void kernel_launch(void* const* d_in, const int* in_sizes, int n_in,
                              void* d_out, int out_size, void* d_ws, size_t ws_size,
                              hipStream_t stream) {
  const float* x       = (const float*)d_in[0];
  const float* conv_w  = (const float*)d_in[1];
  const float* conv_b  = (const float*)d_in[2];
  const float* centers = (const float*)d_in[3];
  float* out = (float*)d_out;

  float* ax_part  = (float*)d_ws;                              // 4 MiB
  float* asum_blk = ax_part + (size_t)N_ * NPB_ * KV_ * C_;    // 16 KiB

  hipLaunchKernelGGL(vlad_fused, dim3(N_ * NPB_), dim3(1024), 0, stream,
                     x, conv_w, conv_b, ax_part, asum_blk);
  hipLaunchKernelGGL(vlad_fin,   dim3(N_ * KV_),  dim3(256), 0, stream,
                     ax_part, asum_blk, centers, out);
}